// Round 7
// baseline (1408.670 us; speedup 1.0000x reference)
//
#include <hip/hip_runtime.h>
#include <math.h>

#define BSZ 4
#define FCH 1024
#define SEQ 2048
#define ICH 2048
#define KW  5
#define EPSV 1e-5f
#define RPAD 2244   // 4 front zero-pad + 2048 rows + slack
#define NCHF 16     // final-norm colred chunks (128 rows each)

typedef __attribute__((ext_vector_type(8))) short bf16x8;
typedef __attribute__((ext_vector_type(4))) float f32x4;
typedef __attribute__((ext_vector_type(4))) unsigned short us4;

__device__ __forceinline__ unsigned short f2bf(float f) {
  union { float f; unsigned u; } v; v.f = f;
  unsigned r = v.u + 0x7fff + ((v.u >> 16) & 1);  // round-to-nearest-even
  return (unsigned short)(r >> 16);
}
__device__ __forceinline__ float bf2f(unsigned short u) {
  union { unsigned u; float f; } v; v.u = (unsigned)u << 16; return v.f;
}

__device__ __forceinline__ void gload_lds16(const void* g, void* l) {
  __builtin_amdgcn_global_load_lds(
      (const __attribute__((address_space(1))) void*)g,
      (__attribute__((address_space(3))) void*)l, 16, 0, 0);
}

// ---------------- input transpose + pos add:  [b][f][s] -> bf16 [b][4+s][f]
__global__ __launch_bounds__(256) void addpos_T_kernel(
    const float* __restrict__ inp, const float* __restrict__ pos,
    unsigned short* __restrict__ X)
{
  __shared__ float t[64][65];
  const int s0 = blockIdx.x * 64, f0 = blockIdx.y * 64, b = blockIdx.z;
  const int a = threadIdx.x & 63, g = threadIdx.x >> 6;
  const float* ib = inp + (size_t)b * FCH * SEQ;
#pragma unroll
  for (int i = 0; i < 16; ++i) {
    const size_t o = (size_t)(f0 + g + i * 4) * SEQ + s0 + a;
    t[a][g + i * 4] = ib[o] + pos[o];
  }
  __syncthreads();
#pragma unroll
  for (int i = 0; i < 16; ++i)
    X[(size_t)b * RPAD * FCH + (size_t)(4 + s0 + g + i * 4) * FCH + f0 + a] =
        f2bf(t[g + i * 4][a]);
}

// zero the 4 leading pad rows of Xbf per batch
__global__ __launch_bounds__(256) void zero_xpad_kernel(unsigned short* __restrict__ X)
{
  const int i = blockIdx.x * 256 + threadIdx.x;  // < BSZ*4*FCH
  const int b = i / (4 * FCH);
  const int r = i % (4 * FCH);
  X[(size_t)b * RPAD * FCH + r] = 0;
}

// divisor [f][s] -> divT [s][f] fp32
__global__ __launch_bounds__(256) void transpose_div_kernel(
    const float* __restrict__ D, float* __restrict__ O)
{
  __shared__ float t[64][65];
  const int s0 = blockIdx.x * 64, f0 = blockIdx.y * 64;
  const int a = threadIdx.x & 63, g = threadIdx.x >> 6;
#pragma unroll
  for (int i = 0; i < 16; ++i)
    t[a][g + i * 4] = D[(size_t)(f0 + g + i * 4) * SEQ + s0 + a];
  __syncthreads();
#pragma unroll
  for (int i = 0; i < 16; ++i)
    O[(size_t)(s0 + g + i * 4) * FCH + f0 + a] = t[g + i * 4][a];
}

// ---------------- weight converts
__global__ __launch_bounds__(256) void cast_bf_kernel(
    const float* __restrict__ I, unsigned short* __restrict__ O)
{
  const size_t i = ((size_t)blockIdx.x * 256 + threadIdx.x) * 4;
  const float4 v = *(const float4*)(I + i);
  us4 o; o.x = f2bf(v.x); o.y = f2bf(v.y); o.z = f2bf(v.z); o.w = f2bf(v.w);
  *(us4*)(O + i) = o;
}

// W1 [m][c][k] fp32 -> O [k][m][c] bf16
__global__ __launch_bounds__(256) void cast_w1_kernel(
    const float* __restrict__ W, unsigned short* __restrict__ O)
{
  const int c = blockIdx.x * 256 + threadIdx.x;
  const int m = blockIdx.y;
  const float* s = W + ((size_t)m * ICH + c) * KW;
#pragma unroll
  for (int k = 0; k < KW; ++k)
    O[((size_t)k * ICH + m) * ICH + c] = f2bf(s[k]);
}

// ---------------- 256x(BN) MFMA GEMM, tap-outer causal shift, 8-phase schedule
// C[b][s][m] = sum_t sum_c A[b][4+s+t-off][c] * W[t][m][c]
// K-tile (BK=64) split into 4 phases (ih, k-slot), each: 8 ds_read_b128 ->
// s_barrier -> lgkmcnt(0) -> setprio+16 MFMA -> s_barrier. Staging in half-units
// (4 gloads): unit1(tau+1) issued in ph0, unit0(tau+2) at tile boundary; counted
// s_waitcnt vmcnt(4) at the boundary keeps 4 loads in flight across barriers.
// BF16OUT: C written as relu()'d bf16 + fused column partial sums to P1/P2.
template <int BN, int NTAPS, int BF16OUT>
__global__ __launch_bounds__(512, 2) void gemm256_kernel(
    const unsigned short* __restrict__ A, const unsigned short* __restrict__ W,
    void* __restrict__ Cv, int M, int K,
    float* __restrict__ P1, float* __restrict__ P2)
{
  extern __shared__ __align__(16) char lds[];
  constexpr int ABYTES = 32768;        // 256 rows x 128B
  constexpr int BBYTES = BN * 128;
  constexpr int BUF = ABYTES + BBYTES;
  constexpr int WN  = BN / 4;          // per-wave m extent (64 or 32)
  constexpr int JF  = BN / 64;         // j-frags per wave (4 or 2)
  constexpr int BH  = BN / 128;        // B row-halves (2 or 1)

  const int tid = threadIdx.x;
  const int ln  = tid & 63;
  const int wv  = tid >> 6;
  const int wr  = wv >> 2;             // s half (128 rows)
  const int wc  = wv & 3;              // m quarter (WN cols)
  const int l15 = ln & 15;
  const int lhi = ln >> 4;

  const int s0 = blockIdx.x * 256;
  const int m0 = blockIdx.y * BN;
  const int b  = blockIdx.z;

  const char* Ab = (const char*)(A + (size_t)b * RPAD * K);
  const char* Wb = (const char*)W;
  const size_t MK = (size_t)M * K;
  const int KT = K >> 6;               // K-tiles of 64
  const int T  = NTAPS * KT;           // global tile count (tap-outer)

  // staging: thread's linear LDS slot -> pre-swizzled global col slot
  const int scs = (((tid & 7) ^ ((tid >> 3) & 7)) << 4);

  f32x4 acc[8][JF] = {};

  // half-unit issue: h=0 -> A rows 0-127 + B rows 0-127 (4 loads);
  //                  h=1 -> A rows 128-255 (+ B rows 128-255 if BN==256)
  auto ISSUE = [&](int tau, int h) {
    const int t  = tau / KT;
    const int k0 = (tau - t * KT) * 64;
    const int roff = (NTAPS == 1) ? 4 : t;
    char* dst = lds + (tau & 1) * BUF;
#pragma unroll
    for (int q = 0; q < 2; ++q) {
      const int row = h * 128 + q * 64 + (tid >> 3);
      gload_lds16(Ab + (size_t)(s0 + row + roff) * ((size_t)K * 2) +
                      (size_t)(k0 * 2 + scs),
                  dst + h * 16384 + q * 8192 + tid * 16);
    }
    if (h == 0 || BH == 2) {
#pragma unroll
      for (int q = 0; q < 2; ++q) {
        const int row = h * 128 + q * 64 + (tid >> 3);
        gload_lds16(Wb + ((size_t)t * MK + (size_t)(m0 + row) * K + k0) * 2 + scs,
                    dst + ABYTES + h * 16384 + q * 8192 + tid * 16);
      }
    }
  };

  // prologue: tile0 fully + unit0 of tile1 in flight
  ISSUE(0, 0); ISSUE(0, 1);
  if (T > 1) {
    ISSUE(1, 0);
    asm volatile("s_waitcnt vmcnt(4)" ::: "memory");
  } else {
    asm volatile("s_waitcnt vmcnt(0)" ::: "memory");
  }
  __builtin_amdgcn_s_barrier();

  for (int tau = 0; tau < T; ++tau) {
    const char* bb = lds + (tau & 1) * BUF;
#pragma unroll
    for (int ph = 0; ph < 4; ++ph) {
      const int ih = ph >> 1, ks = ph & 1;
      bf16x8 af[4], bw[JF];
#pragma unroll
      for (int i = 0; i < 4; ++i) {
        const int r = wr * 128 + ih * 64 + i * 16 + l15;
        af[i] = *(const bf16x8*)(bb + r * 128 +
                                 ((lhi * 16 + ks * 64) ^ ((r & 7) << 4)));
      }
#pragma unroll
      for (int j = 0; j < JF; ++j) {
        const int r = wc * WN + j * 16 + l15;
        bw[j] = *(const bf16x8*)(bb + ABYTES + r * 128 +
                                 ((lhi * 16 + ks * 64) ^ ((r & 7) << 4)));
      }
      if (ph == 0 && tau + 1 < T) ISSUE(tau + 1, 1);
      __builtin_amdgcn_s_barrier();
      asm volatile("s_waitcnt lgkmcnt(0)" ::: "memory");
      __builtin_amdgcn_s_setprio(1);
#pragma unroll
      for (int i = 0; i < 4; ++i)
#pragma unroll
        for (int j = 0; j < JF; ++j)
          acc[ih * 4 + i][j] = __builtin_amdgcn_mfma_f32_16x16x32_bf16(
              af[i], bw[j], acc[ih * 4 + i][j], 0, 0, 0);
      __builtin_amdgcn_s_setprio(0);
      __builtin_amdgcn_s_barrier();
    }
    // tile boundary: issue unit0(tau+2) into the buffer just finished reading,
    // then counted drain of tile tau+1's loads (leave tau+2's 4 in flight)
    if (tau + 2 < T) {
      ISSUE(tau + 2, 0);
      asm volatile("s_waitcnt vmcnt(4)" ::: "memory");
      __builtin_amdgcn_s_barrier();
    } else if (tau + 1 < T) {
      asm volatile("s_waitcnt vmcnt(0)" ::: "memory");
      __builtin_amdgcn_s_barrier();
    }
  }

  if constexpr (BF16OUT) {
    // relu'd bf16 C + fused column partial sums (chunk = this block's 256 rows)
    unsigned short* Cb = (unsigned short*)Cv + (size_t)b * SEQ * M;
    float S[JF] = {}, Q[JF] = {};
#pragma unroll
    for (int i = 0; i < 8; ++i) {
      const int sb = s0 + wr * 128 + i * 16 + lhi * 4;
#pragma unroll
      for (int j = 0; j < JF; ++j) {
        const int m = m0 + wc * WN + j * 16 + l15;
#pragma unroll
        for (int r = 0; r < 4; ++r) {
          const float x = fmaxf(acc[i][j][r], 0.f);
          S[j] += x; Q[j] += x * x;
          Cb[(size_t)(sb + r) * M + m] = f2bf(x);
        }
      }
    }
#pragma unroll
    for (int j = 0; j < JF; ++j) {
      S[j] += __shfl_xor(S[j], 16, 64); S[j] += __shfl_xor(S[j], 32, 64);
      Q[j] += __shfl_xor(Q[j], 16, 64); Q[j] += __shfl_xor(Q[j], 32, 64);
    }
    float* SL = (float*)lds;                 // [2][4][JF][16]
    float* QL = SL + 2 * 4 * JF * 16;
    __syncthreads();                         // all loop LDS traffic retired
    if (lhi == 0) {
#pragma unroll
      for (int j = 0; j < JF; ++j) {
        SL[((wr * 4 + wc) * JF + j) * 16 + l15] = S[j];
        QL[((wr * 4 + wc) * JF + j) * 16 + l15] = Q[j];
      }
    }
    __syncthreads();
    if (wr == 0 && lhi == 0) {
#pragma unroll
      for (int j = 0; j < JF; ++j) {
        const int m = m0 + wc * WN + j * 16 + l15;
        const size_t o = ((size_t)b * (SEQ / 256) + blockIdx.x) * M + m;
        P1[o] = SL[((0 * 4 + wc) * JF + j) * 16 + l15] +
                SL[((1 * 4 + wc) * JF + j) * 16 + l15];
        P2[o] = QL[((0 * 4 + wc) * JF + j) * 16 + l15] +
                QL[((1 * 4 + wc) * JF + j) * 16 + l15];
      }
    }
  } else {
    float* Cb = (float*)Cv + (size_t)b * SEQ * M;
#pragma unroll
    for (int i = 0; i < 8; ++i) {
      const int sb = s0 + wr * 128 + i * 16 + lhi * 4;
#pragma unroll
      for (int j = 0; j < JF; ++j) {
        const int m = m0 + wc * WN + j * 16 + l15;
#pragma unroll
        for (int r = 0; r < 4; ++r)
          Cb[(size_t)(sb + r) * M + m] = acc[i][j][r];
      }
    }
  }
}

// ---------------- colred (final norm only): partial sums over 128-row chunks
__global__ __launch_bounds__(256) void colred_kernel(
    const float* __restrict__ Cf, float* __restrict__ P1,
    float* __restrict__ P2, int M)
{
  const int b = blockIdx.z;
  const int mi = threadIdx.x & 63;
  const int sg = threadIdx.x >> 6;
  const int m = blockIdx.x * 64 + mi;
  const int s0 = blockIdx.y * 128;
  const float* src = Cf + ((size_t)b * SEQ + s0) * M + m;
  float sum = 0.f, sq = 0.f;
  for (int s = sg; s < 128; s += 4) {
    const float x = fmaxf(src[(size_t)s * M], 0.f);
    sum += x; sq += x * x;
  }
  __shared__ float rs[4][64], rq[4][64];
  rs[sg][mi] = sum; rq[sg][mi] = sq;
  __syncthreads();
  if (sg == 0) {
    const size_t o = ((size_t)b * NCHF + blockIdx.y) * M + m;
    P1[o] = rs[0][mi] + rs[1][mi] + rs[2][mi] + rs[3][mi];
    P2[o] = rq[0][mi] + rq[1][mi] + rq[2][mi] + rq[3][mi];
  }
}

// colfin: mean/scale per (b,m) from nchunk partials.  MS [b][2][M]
__global__ __launch_bounds__(256) void colfin_kernel(
    const float* __restrict__ P1, const float* __restrict__ P2,
    float* __restrict__ MS, int M, int nchunk)
{
  const int i = blockIdx.x * 256 + threadIdx.x;  // < BSZ*M
  const int b = i / M, m = i % M;
  float S1 = 0.f, S2 = 0.f;
  for (int c = 0; c < nchunk; ++c) {
    S1 += P1[((size_t)b * nchunk + c) * M + m];
    S2 += P2[((size_t)b * nchunk + c) * M + m];
  }
  const float mean = S1 * (1.f / SEQ);
  const float ss = fmaxf(S2 - SEQ * mean * mean, 0.f);
  const float scl = sqrtf((float)SEQ) / (sqrtf(ss) + EPSV);
  MS[((size_t)b * 2 + 0) * M + m] = mean;
  MS[((size_t)b * 2 + 1) * M + m] = scl;
}

// colapply: (relu'd bf16 C - mean)*scl -> bf16 padded activation buffer
__global__ __launch_bounds__(256) void colapply_kernel(
    const unsigned short* __restrict__ Cf, const float* __restrict__ MS,
    unsigned short* __restrict__ Ob, int M)
{
  const int b = blockIdx.z;
  const int mi = threadIdx.x & 63;
  const int sg = threadIdx.x >> 6;
  const int m = blockIdx.x * 64 + mi;
  const int s0 = blockIdx.y * 128;
  const float mean = MS[((size_t)b * 2 + 0) * M + m];
  const float scl  = MS[((size_t)b * 2 + 1) * M + m];
  const unsigned short* src = Cf + ((size_t)b * SEQ + s0) * M + m;
  unsigned short* dst = Ob + ((size_t)b * RPAD + 4 + s0) * M + m;
  if (blockIdx.y == 0 && sg == 0) {
#pragma unroll
    for (int r = 0; r < 4; ++r) Ob[((size_t)b * RPAD + r) * M + m] = 0;
  }
  for (int s = sg; s < 128; s += 4)
    dst[(size_t)s * M] = f2bf((bf2f(src[(size_t)s * M]) - mean) * scl);
}

// ---------------- cumsum over f (fast dim) + divide/scale/shift, in place on Dp
__global__ __launch_bounds__(256) void combine_kernel(
    float* __restrict__ Dp, const float* __restrict__ divT,
    const float* __restrict__ Sc, const float* __restrict__ Sh)
{
  const int row = blockIdx.x * 4 + (threadIdx.x >> 6);  // (b,s) flat
  const int b = row >> 11, s = row & 2047;
  const int ln = threadIdx.x & 63;
  const size_t base = ((size_t)b * SEQ + s) * FCH;
  const float* dv = divT + (size_t)s * FCH;
  float carry = 0.f;
  for (int c0 = 0; c0 < FCH; c0 += 64) {
    float x = Dp[base + c0 + ln];
#pragma unroll
    for (int d = 1; d < 64; d <<= 1) {
      const float t = __shfl_up(x, d, 64);
      if (ln >= d) x += t;
    }
    x += carry;
    carry = __shfl(x, 63, 64);
    Dp[base + c0 + ln] = x / dv[c0 + ln] * Sc[base + c0 + ln] + Sh[base + c0 + ln];
  }
}

// ---------------- final apply: out[b][f][s] = inp + (relu(Df)-mean)*scl, transposed
__global__ __launch_bounds__(256) void final_apply_kernel(
    const float* __restrict__ Df, const float* __restrict__ MS,
    const float* __restrict__ inp, float* __restrict__ out)
{
  __shared__ float tile[64][65];
  const int b = blockIdx.z;
  const int s0 = blockIdx.x * 64, f0 = blockIdx.y * 64;
  const int a = threadIdx.x & 63, g = threadIdx.x >> 6;
  const float mean = MS[((size_t)b * 2 + 0) * FCH + f0 + a];
  const float scl  = MS[((size_t)b * 2 + 1) * FCH + f0 + a];
#pragma unroll
  for (int i = 0; i < 16; ++i) {
    const int s = g + i * 4;
    const float x = fmaxf(Df[((size_t)b * SEQ + s0 + s) * FCH + f0 + a], 0.f);
    tile[s][a] = (x - mean) * scl;
  }
  __syncthreads();
#pragma unroll
  for (int i = 0; i < 16; ++i) {
    const int f = g + i * 4;
    const size_t o = ((size_t)b * FCH + f0 + f) * SEQ + s0 + a;
    out[o] = inp[o] + tile[a][f];
  }
}

extern "C" void kernel_launch(void* const* d_in, const int* in_sizes, int n_in,
                              void* d_out, int out_size, void* d_ws, size_t ws_size,
                              hipStream_t stream)
{
  const float* inp     = (const float*)d_in[0];
  const float* pos     = (const float*)d_in[1];
  const float* divisor = (const float*)d_in[2];
  const float* w_[9];
  for (int i = 0; i < 9; ++i) w_[i] = (const float*)d_in[3 + i];
  float* out = (float*)d_out;

  // workspace layout (~250 MB)
  char* p = (char*)d_ws;
  float*          divT = (float*)p;          p += (size_t)SEQ * FCH * 4;
  unsigned short* Xbf  = (unsigned short*)p; p += (size_t)BSZ * RPAD * FCH * 2;
  unsigned short* T0b  = (unsigned short*)p; p += (size_t)BSZ * RPAD * ICH * 2;
  unsigned short* Cfb  = (unsigned short*)p; p += (size_t)BSZ * SEQ * ICH * 2;
  float*          Df   = (float*)p;          p += (size_t)BSZ * SEQ * FCH * 4;
  float*          Sf   = (float*)p;          p += (size_t)BSZ * SEQ * FCH * 4;
  float*          Hf   = (float*)p;          p += (size_t)BSZ * SEQ * FCH * 4;
  unsigned short* w0b  = (unsigned short*)p; p += (size_t)ICH * FCH * 2;
  unsigned short* w1b  = (unsigned short*)p; p += (size_t)KW * ICH * ICH * 2;
  unsigned short* w2b  = (unsigned short*)p; p += (size_t)FCH * ICH * 2;
  float*          P1   = (float*)p;          p += (size_t)BSZ * NCHF * ICH * 4;
  float*          P2   = (float*)p;          p += (size_t)BSZ * NCHF * ICH * 4;
  float*          MS   = (float*)p;          p += (size_t)BSZ * 2 * ICH * 4;

  // allow >64KB dynamic LDS for the GEMM instantiations
  hipFuncSetAttribute((const void*)gemm256_kernel<256, 1, 1>,
                      hipFuncAttributeMaxDynamicSharedMemorySize, 131072);
  hipFuncSetAttribute((const void*)gemm256_kernel<256, 5, 1>,
                      hipFuncAttributeMaxDynamicSharedMemorySize, 131072);
  hipFuncSetAttribute((const void*)gemm256_kernel<128, 1, 0>,
                      hipFuncAttributeMaxDynamicSharedMemorySize, 98304);

  zero_xpad_kernel<<<BSZ * 4 * FCH / 256, 256, 0, stream>>>(Xbf);
  addpos_T_kernel<<<dim3(SEQ / 64, FCH / 64, BSZ), 256, 0, stream>>>(inp, pos, Xbf);
  transpose_div_kernel<<<dim3(SEQ / 64, FCH / 64), 256, 0, stream>>>(divisor, divT);

  // colfin+colapply after a BF16OUT GEMM (stats already in P1/P2, 8 chunks)
  auto act_norm = [&](unsigned short* dst, int M) {
    colfin_kernel<<<(BSZ * M) / 256, 256, 0, stream>>>(P1, P2, MS, M, 8);
    colapply_kernel<<<dim3(M / 64, NCHF, BSZ), 256, 0, stream>>>(Cfb, MS, dst, M);
  };

  auto run_ff = [&](const float* w0, const float* w1, const float* w2, float* dst) {
    cast_bf_kernel<<<(ICH * FCH) / 1024, 256, 0, stream>>>(w0, w0b);
    cast_w1_kernel<<<dim3(ICH / 256, ICH), 256, 0, stream>>>(w1, w1b);
    cast_bf_kernel<<<(FCH * ICH) / 1024, 256, 0, stream>>>(w2, w2b);
    // conv0: M=ICH, K=FCH
    gemm256_kernel<256, 1, 1><<<dim3(SEQ / 256, ICH / 256, BSZ), 512, 131072, stream>>>(
        Xbf, w0b, Cfb, ICH, FCH, P1, P2);
    act_norm(T0b, ICH);
    // conv1: 5 causal taps (tap-outer), M=ICH, K=ICH
    gemm256_kernel<256, 5, 1><<<dim3(SEQ / 256, ICH / 256, BSZ), 512, 131072, stream>>>(
        T0b, w1b, Cfb, ICH, ICH, P1, P2);
    act_norm(T0b, ICH);
    // conv2: M=FCH, K=ICH, fp32 out (BN=128 keeps 256 blocks)
    gemm256_kernel<128, 1, 0><<<dim3(SEQ / 256, FCH / 128, BSZ), 512, 98304, stream>>>(
        T0b, w2b, dst, FCH, ICH, P1, P2);
  };

  run_ff(w_[0], w_[1], w_[2], Df);  // depth
  run_ff(w_[3], w_[4], w_[5], Sf);  // scale
  run_ff(w_[6], w_[7], w_[8], Hf);  // shift

  combine_kernel<<<(BSZ * SEQ) / 4, 256, 0, stream>>>(Df, divT, Sf, Hf);

  // final act_norm over s (per (b,f)) on combined Df, then transpose + residual
  colred_kernel<<<dim3(FCH / 64, NCHF, BSZ), 256, 0, stream>>>(Df, P1, P2, FCH);
  colfin_kernel<<<(BSZ * FCH) / 256, 256, 0, stream>>>(P1, P2, MS, FCH, NCHF);
  final_apply_kernel<<<dim3(SEQ / 64, FCH / 64, BSZ), 256, 0, stream>>>(
      Df, MS, inp, out);
}

// Round 8
// 1188.729 us; speedup vs baseline: 1.1850x; 1.1850x over previous
//
#include <hip/hip_runtime.h>
#include <math.h>

#define BSZ 4
#define FCH 1024
#define SEQ 2048
#define ICH 2048
#define KW  5
#define EPSV 1e-5f
#define RPAD 2244   // 4 front zero-pad + 2048 rows + slack
#define NCHF 16     // final-norm colred chunks (128 rows each)

typedef __attribute__((ext_vector_type(8))) short bf16x8;
typedef __attribute__((ext_vector_type(4))) float f32x4;
typedef __attribute__((ext_vector_type(4))) unsigned short us4;

__device__ __forceinline__ unsigned short f2bf(float f) {
  union { float f; unsigned u; } v; v.f = f;
  unsigned r = v.u + 0x7fff + ((v.u >> 16) & 1);  // round-to-nearest-even
  return (unsigned short)(r >> 16);
}
__device__ __forceinline__ float bf2f(unsigned short u) {
  union { unsigned u; float f; } v; v.u = (unsigned)u << 16; return v.f;
}

__device__ __forceinline__ void gload_lds16(const void* g, void* l) {
  __builtin_amdgcn_global_load_lds(
      (const __attribute__((address_space(1))) void*)g,
      (__attribute__((address_space(3))) void*)l, 16, 0, 0);
}

// ---------------- input transpose + pos add:  [b][f][s] -> bf16 [b][4+s][f]
__global__ __launch_bounds__(256) void addpos_T_kernel(
    const float* __restrict__ inp, const float* __restrict__ pos,
    unsigned short* __restrict__ X)
{
  __shared__ float t[64][65];
  const int s0 = blockIdx.x * 64, f0 = blockIdx.y * 64, b = blockIdx.z;
  const int a = threadIdx.x & 63, g = threadIdx.x >> 6;
  const float* ib = inp + (size_t)b * FCH * SEQ;
#pragma unroll
  for (int i = 0; i < 16; ++i) {
    const size_t o = (size_t)(f0 + g + i * 4) * SEQ + s0 + a;
    t[a][g + i * 4] = ib[o] + pos[o];
  }
  __syncthreads();
#pragma unroll
  for (int i = 0; i < 16; ++i)
    X[(size_t)b * RPAD * FCH + (size_t)(4 + s0 + g + i * 4) * FCH + f0 + a] =
        f2bf(t[g + i * 4][a]);
}

// zero the 4 leading pad rows of Xbf per batch
__global__ __launch_bounds__(256) void zero_xpad_kernel(unsigned short* __restrict__ X)
{
  const int i = blockIdx.x * 256 + threadIdx.x;  // < BSZ*4*FCH
  const int b = i / (4 * FCH);
  const int r = i % (4 * FCH);
  X[(size_t)b * RPAD * FCH + r] = 0;
}

// divisor [f][s] -> divT [s][f] fp32
__global__ __launch_bounds__(256) void transpose_div_kernel(
    const float* __restrict__ D, float* __restrict__ O)
{
  __shared__ float t[64][65];
  const int s0 = blockIdx.x * 64, f0 = blockIdx.y * 64;
  const int a = threadIdx.x & 63, g = threadIdx.x >> 6;
#pragma unroll
  for (int i = 0; i < 16; ++i)
    t[a][g + i * 4] = D[(size_t)(f0 + g + i * 4) * SEQ + s0 + a];
  __syncthreads();
#pragma unroll
  for (int i = 0; i < 16; ++i)
    O[(size_t)(s0 + g + i * 4) * FCH + f0 + a] = t[g + i * 4][a];
}

// ---------------- weight converts
__global__ __launch_bounds__(256) void cast_bf_kernel(
    const float* __restrict__ I, unsigned short* __restrict__ O)
{
  const size_t i = ((size_t)blockIdx.x * 256 + threadIdx.x) * 4;
  const float4 v = *(const float4*)(I + i);
  us4 o; o.x = f2bf(v.x); o.y = f2bf(v.y); o.z = f2bf(v.z); o.w = f2bf(v.w);
  *(us4*)(O + i) = o;
}

// W1 [m][c][k] fp32 -> O [k][m][c] bf16
__global__ __launch_bounds__(256) void cast_w1_kernel(
    const float* __restrict__ W, unsigned short* __restrict__ O)
{
  const int c = blockIdx.x * 256 + threadIdx.x;
  const int m = blockIdx.y;
  const float* s = W + ((size_t)m * ICH + c) * KW;
#pragma unroll
  for (int k = 0; k < KW; ++k)
    O[((size_t)k * ICH + m) * ICH + c] = f2bf(s[k]);
}

// ---------------- 256x(BN) double-buffered MFMA GEMM, tap-outer causal shift
// C[b][s][m] = sum_t sum_c A[b][4+s+t-off][c] * W[t][m][c]
// A bf16 [BSZ][RPAD][K] (rows 0..3 zero), W bf16 [NTAPS][M][K].
// BM=256, BK=64, 512 threads = 8 waves (2 s-halves x 4 m-cols), LDS XOR-swizzle,
// single barrier per K-tile, stage(t+1) issued at start of tile t (round-5 proven).
// OUTMODE: 0 = raw fp32; 1 = relu'd bf16 + fused column stats P1/P2; 2 = raw bf16.
template <int BN, int NTAPS, int OUTMODE>
__global__ __launch_bounds__(512, 2) void gemm256_kernel(
    const unsigned short* __restrict__ A, const unsigned short* __restrict__ W,
    void* __restrict__ Cv, int M, int K,
    float* __restrict__ P1, float* __restrict__ P2)
{
  extern __shared__ __align__(16) char lds[];
  constexpr int ABYTES = 32768;        // 256 rows x 128B
  constexpr int BBYTES = BN * 128;
  constexpr int BUF = ABYTES + BBYTES;
  constexpr int WN  = BN / 4;          // per-wave m extent (64 or 32)
  constexpr int JF  = BN / 64;         // j-frags per wave (4 or 2)
  constexpr int JF2 = BN / 128;        // j-frags per jh half (2 or 1)

  const int tid = threadIdx.x;
  const int ln  = tid & 63;
  const int wv  = tid >> 6;
  const int wr  = wv >> 2;             // s half (128 rows)
  const int wc  = wv & 3;              // m quarter (WN cols)
  const int l15 = ln & 15;
  const int lhi = ln >> 4;

  const int s0 = blockIdx.x * 256;
  const int m0 = blockIdx.y * BN;
  const int b  = blockIdx.z;

  const char* Ab = (const char*)(A + (size_t)b * RPAD * K);
  const char* Wb = (const char*)W;
  const size_t MK = (size_t)M * K;
  const int KT = K >> 6;               // K-tiles of 64

  // staging: thread's linear LDS slot (row, col) -> pre-swizzled global col
  const int scs  = (((tid & 7) ^ ((tid >> 3) & 7)) << 4);
  // fragment reads: swizzled col bytes for k-slots 0,1
  const int rxor = (l15 & 7) << 4;
  const int cbx0 = (lhi * 16) ^ rxor;
  const int cbx1 = (lhi * 16 + 64) ^ rxor;

  f32x4 acc[8][JF] = {};

  auto STAGE = [&](int t, int k0, int pb) {
    const int roff = (NTAPS == 1) ? 4 : t;
    char* dst = lds + pb * BUF;
#pragma unroll
    for (int q = 0; q < 4; ++q) {
      const int row = (q * 512 + tid) >> 3;
      gload_lds16(Ab + (size_t)(s0 + row + roff) * ((size_t)K * 2) +
                      (size_t)(k0 * 2 + scs),
                  dst + q * 8192 + tid * 16);
    }
#pragma unroll
    for (int q = 0; q < BN / 64; ++q) {
      const int row = (q * 512 + tid) >> 3;
      gload_lds16(Wb + ((size_t)t * MK + (size_t)(m0 + row) * K + k0) * 2 + scs,
                  dst + ABYTES + q * 8192 + tid * 16);
    }
  };

  auto COMPUTE = [&](int pb) {
    const char* bb = lds + pb * BUF;
    // hoisted B fragments: read once per tile (8 or 4 reads), reused by both ih
    bf16x8 bw[2][JF2][2];
#pragma unroll
    for (int jh = 0; jh < 2; ++jh)
#pragma unroll
      for (int j = 0; j < JF2; ++j) {
        const int r = ABYTES + (wc * WN + jh * (WN / 2) + j * 16 + l15) * 128;
        bw[jh][j][0] = *(const bf16x8*)(bb + r + cbx0);
        bw[jh][j][1] = *(const bf16x8*)(bb + r + cbx1);
      }
#pragma unroll
    for (int ih = 0; ih < 2; ++ih) {
      bf16x8 af[4][2];
#pragma unroll
      for (int i = 0; i < 4; ++i) {
        const int r = (wr * 128 + ih * 64 + i * 16 + l15) * 128;
        af[i][0] = *(const bf16x8*)(bb + r + cbx0);
        af[i][1] = *(const bf16x8*)(bb + r + cbx1);
      }
#pragma unroll
      for (int jh = 0; jh < 2; ++jh) {
        __builtin_amdgcn_s_setprio(1);
#pragma unroll
        for (int i = 0; i < 4; ++i)
#pragma unroll
          for (int j = 0; j < JF2; ++j) {
            acc[ih * 4 + i][jh * JF2 + j] = __builtin_amdgcn_mfma_f32_16x16x32_bf16(
                af[i][0], bw[jh][j][0], acc[ih * 4 + i][jh * JF2 + j], 0, 0, 0);
            acc[ih * 4 + i][jh * JF2 + j] = __builtin_amdgcn_mfma_f32_16x16x32_bf16(
                af[i][1], bw[jh][j][1], acc[ih * 4 + i][jh * JF2 + j], 0, 0, 0);
          }
        __builtin_amdgcn_s_setprio(0);
      }
    }
  };

  STAGE(0, 0, 0);
  asm volatile("s_waitcnt vmcnt(0)" ::: "memory");
  __syncthreads();
  int p = 0;
  for (int t = 0; t < NTAPS; ++t) {
    for (int kt = 0; kt < KT; ++kt) {
      int ntp = t, nk = kt + 1;
      if (nk == KT) { nk = 0; ++ntp; }
      if (ntp < NTAPS) STAGE(ntp, nk * 64, p ^ 1);
      COMPUTE(p);
      asm volatile("s_waitcnt vmcnt(0)" ::: "memory");
      __syncthreads();
      p ^= 1;
    }
  }

  if constexpr (OUTMODE == 1) {
    // relu'd bf16 C + fused column partial sums (chunk = this block's 256 rows)
    unsigned short* Cb = (unsigned short*)Cv + (size_t)b * SEQ * M;
    float S[JF] = {}, Q[JF] = {};
#pragma unroll
    for (int i = 0; i < 8; ++i) {
      const int sb = s0 + wr * 128 + i * 16 + lhi * 4;
#pragma unroll
      for (int j = 0; j < JF; ++j) {
        const int m = m0 + wc * WN + j * 16 + l15;
#pragma unroll
        for (int r = 0; r < 4; ++r) {
          const float x = fmaxf(acc[i][j][r], 0.f);
          S[j] += x; Q[j] += x * x;
          Cb[(size_t)(sb + r) * M + m] = f2bf(x);
        }
      }
    }
#pragma unroll
    for (int j = 0; j < JF; ++j) {
      S[j] += __shfl_xor(S[j], 16, 64); S[j] += __shfl_xor(S[j], 32, 64);
      Q[j] += __shfl_xor(Q[j], 16, 64); Q[j] += __shfl_xor(Q[j], 32, 64);
    }
    float* SL = (float*)lds;                 // [2][4][JF][16]
    float* QL = SL + 2 * 4 * JF * 16;
    if (lhi == 0) {
#pragma unroll
      for (int j = 0; j < JF; ++j) {
        SL[((wr * 4 + wc) * JF + j) * 16 + l15] = S[j];
        QL[((wr * 4 + wc) * JF + j) * 16 + l15] = Q[j];
      }
    }
    __syncthreads();
    if (wr == 0 && lhi == 0) {
#pragma unroll
      for (int j = 0; j < JF; ++j) {
        const int m = m0 + wc * WN + j * 16 + l15;
        const size_t o = ((size_t)b * (SEQ / 256) + blockIdx.x) * M + m;
        P1[o] = SL[((0 * 4 + wc) * JF + j) * 16 + l15] +
                SL[((1 * 4 + wc) * JF + j) * 16 + l15];
        P2[o] = QL[((0 * 4 + wc) * JF + j) * 16 + l15] +
                QL[((1 * 4 + wc) * JF + j) * 16 + l15];
      }
    }
  } else if constexpr (OUTMODE == 2) {
    unsigned short* Cb = (unsigned short*)Cv + (size_t)b * SEQ * M;
#pragma unroll
    for (int i = 0; i < 8; ++i) {
      const int sb = s0 + wr * 128 + i * 16 + lhi * 4;
#pragma unroll
      for (int j = 0; j < JF; ++j) {
        const int m = m0 + wc * WN + j * 16 + l15;
#pragma unroll
        for (int r = 0; r < 4; ++r)
          Cb[(size_t)(sb + r) * M + m] = f2bf(acc[i][j][r]);
      }
    }
  } else {
    float* Cb = (float*)Cv + (size_t)b * SEQ * M;
#pragma unroll
    for (int i = 0; i < 8; ++i) {
      const int sb = s0 + wr * 128 + i * 16 + lhi * 4;
#pragma unroll
      for (int j = 0; j < JF; ++j) {
        const int m = m0 + wc * WN + j * 16 + l15;
#pragma unroll
        for (int r = 0; r < 4; ++r)
          Cb[(size_t)(sb + r) * M + m] = acc[i][j][r];
      }
    }
  }
}

// ---------------- colred (final norm only): partial sums over 128-row chunks
__global__ __launch_bounds__(256) void colred_kernel(
    const float* __restrict__ Cf, float* __restrict__ P1,
    float* __restrict__ P2, int M)
{
  const int b = blockIdx.z;
  const int mi = threadIdx.x & 63;
  const int sg = threadIdx.x >> 6;
  const int m = blockIdx.x * 64 + mi;
  const int s0 = blockIdx.y * 128;
  const float* src = Cf + ((size_t)b * SEQ + s0) * M + m;
  float sum = 0.f, sq = 0.f;
  for (int s = sg; s < 128; s += 4) {
    const float x = fmaxf(src[(size_t)s * M], 0.f);
    sum += x; sq += x * x;
  }
  __shared__ float rs[4][64], rq[4][64];
  rs[sg][mi] = sum; rq[sg][mi] = sq;
  __syncthreads();
  if (sg == 0) {
    const size_t o = ((size_t)b * NCHF + blockIdx.y) * M + m;
    P1[o] = rs[0][mi] + rs[1][mi] + rs[2][mi] + rs[3][mi];
    P2[o] = rq[0][mi] + rq[1][mi] + rq[2][mi] + rq[3][mi];
  }
}

// colfin: mean/scale per (b,m) from nchunk partials.  MS [b][2][M]
__global__ __launch_bounds__(256) void colfin_kernel(
    const float* __restrict__ P1, const float* __restrict__ P2,
    float* __restrict__ MS, int M, int nchunk)
{
  const int i = blockIdx.x * 256 + threadIdx.x;  // < BSZ*M
  const int b = i / M, m = i % M;
  float S1 = 0.f, S2 = 0.f;
  for (int c = 0; c < nchunk; ++c) {
    S1 += P1[((size_t)b * nchunk + c) * M + m];
    S2 += P2[((size_t)b * nchunk + c) * M + m];
  }
  const float mean = S1 * (1.f / SEQ);
  const float ss = fmaxf(S2 - SEQ * mean * mean, 0.f);
  const float scl = sqrtf((float)SEQ) / (sqrtf(ss) + EPSV);
  MS[((size_t)b * 2 + 0) * M + m] = mean;
  MS[((size_t)b * 2 + 1) * M + m] = scl;
}

// colapply: (relu'd bf16 C - mean)*scl -> bf16 padded activation buffer
__global__ __launch_bounds__(256) void colapply_kernel(
    const unsigned short* __restrict__ Cf, const float* __restrict__ MS,
    unsigned short* __restrict__ Ob, int M)
{
  const int b = blockIdx.z;
  const int mi = threadIdx.x & 63;
  const int sg = threadIdx.x >> 6;
  const int m = blockIdx.x * 64 + mi;
  const int s0 = blockIdx.y * 128;
  const float mean = MS[((size_t)b * 2 + 0) * M + m];
  const float scl  = MS[((size_t)b * 2 + 1) * M + m];
  const unsigned short* src = Cf + ((size_t)b * SEQ + s0) * M + m;
  unsigned short* dst = Ob + ((size_t)b * RPAD + 4 + s0) * M + m;
  if (blockIdx.y == 0 && sg == 0) {
#pragma unroll
    for (int r = 0; r < 4; ++r) Ob[((size_t)b * RPAD + r) * M + m] = 0;
  }
  for (int s = sg; s < 128; s += 4)
    dst[(size_t)s * M] = f2bf((bf2f(src[(size_t)s * M]) - mean) * scl);
}

// ---------------- cumsum over f (fast dim) + divide/scale(bf16)/shift(bf16)
__global__ __launch_bounds__(256) void combine_kernel(
    float* __restrict__ Dp, const float* __restrict__ divT,
    const unsigned short* __restrict__ Sc, const unsigned short* __restrict__ Sh)
{
  const int row = blockIdx.x * 4 + (threadIdx.x >> 6);  // (b,s) flat
  const int b = row >> 11, s = row & 2047;
  const int ln = threadIdx.x & 63;
  const size_t base = ((size_t)b * SEQ + s) * FCH;
  const float* dv = divT + (size_t)s * FCH;
  float carry = 0.f;
  for (int c0 = 0; c0 < FCH; c0 += 64) {
    float x = Dp[base + c0 + ln];
#pragma unroll
    for (int d = 1; d < 64; d <<= 1) {
      const float t = __shfl_up(x, d, 64);
      if (ln >= d) x += t;
    }
    x += carry;
    carry = __shfl(x, 63, 64);
    Dp[base + c0 + ln] = x / dv[c0 + ln] * bf2f(Sc[base + c0 + ln]) +
                         bf2f(Sh[base + c0 + ln]);
  }
}

// ---------------- final apply: out[b][f][s] = inp + (relu(Df)-mean)*scl, transposed
__global__ __launch_bounds__(256) void final_apply_kernel(
    const float* __restrict__ Df, const float* __restrict__ MS,
    const float* __restrict__ inp, float* __restrict__ out)
{
  __shared__ float tile[64][65];
  const int b = blockIdx.z;
  const int s0 = blockIdx.x * 64, f0 = blockIdx.y * 64;
  const int a = threadIdx.x & 63, g = threadIdx.x >> 6;
  const float mean = MS[((size_t)b * 2 + 0) * FCH + f0 + a];
  const float scl  = MS[((size_t)b * 2 + 1) * FCH + f0 + a];
#pragma unroll
  for (int i = 0; i < 16; ++i) {
    const int s = g + i * 4;
    const float x = fmaxf(Df[((size_t)b * SEQ + s0 + s) * FCH + f0 + a], 0.f);
    tile[s][a] = (x - mean) * scl;
  }
  __syncthreads();
#pragma unroll
  for (int i = 0; i < 16; ++i) {
    const int f = g + i * 4;
    const size_t o = ((size_t)b * FCH + f0 + f) * SEQ + s0 + a;
    out[o] = inp[o] + tile[a][f];
  }
}

extern "C" void kernel_launch(void* const* d_in, const int* in_sizes, int n_in,
                              void* d_out, int out_size, void* d_ws, size_t ws_size,
                              hipStream_t stream)
{
  const float* inp     = (const float*)d_in[0];
  const float* pos     = (const float*)d_in[1];
  const float* divisor = (const float*)d_in[2];
  const float* w_[9];
  for (int i = 0; i < 9; ++i) w_[i] = (const float*)d_in[3 + i];
  float* out = (float*)d_out;

  // workspace layout (~215 MB)
  char* p = (char*)d_ws;
  float*          divT = (float*)p;          p += (size_t)SEQ * FCH * 4;
  unsigned short* Xbf  = (unsigned short*)p; p += (size_t)BSZ * RPAD * FCH * 2;
  unsigned short* T0b  = (unsigned short*)p; p += (size_t)BSZ * RPAD * ICH * 2;
  unsigned short* Cfb  = (unsigned short*)p; p += (size_t)BSZ * SEQ * ICH * 2;
  float*          Df   = (float*)p;          p += (size_t)BSZ * SEQ * FCH * 4;
  unsigned short* Sfb  = (unsigned short*)p; p += (size_t)BSZ * SEQ * FCH * 2;
  unsigned short* Hfb  = (unsigned short*)p; p += (size_t)BSZ * SEQ * FCH * 2;
  unsigned short* w0b  = (unsigned short*)p; p += (size_t)ICH * FCH * 2;
  unsigned short* w1b  = (unsigned short*)p; p += (size_t)KW * ICH * ICH * 2;
  unsigned short* w2b  = (unsigned short*)p; p += (size_t)FCH * ICH * 2;
  float*          P1   = (float*)p;          p += (size_t)BSZ * NCHF * ICH * 4;
  float*          P2   = (float*)p;          p += (size_t)BSZ * NCHF * ICH * 4;
  float*          MS   = (float*)p;          p += (size_t)BSZ * 2 * ICH * 4;

  // allow >64KB dynamic LDS for the GEMM instantiations
  hipFuncSetAttribute((const void*)gemm256_kernel<256, 1, 1>,
                      hipFuncAttributeMaxDynamicSharedMemorySize, 131072);
  hipFuncSetAttribute((const void*)gemm256_kernel<256, 5, 1>,
                      hipFuncAttributeMaxDynamicSharedMemorySize, 131072);
  hipFuncSetAttribute((const void*)gemm256_kernel<128, 1, 0>,
                      hipFuncAttributeMaxDynamicSharedMemorySize, 98304);
  hipFuncSetAttribute((const void*)gemm256_kernel<128, 1, 2>,
                      hipFuncAttributeMaxDynamicSharedMemorySize, 98304);

  zero_xpad_kernel<<<BSZ * 4 * FCH / 256, 256, 0, stream>>>(Xbf);
  addpos_T_kernel<<<dim3(SEQ / 64, FCH / 64, BSZ), 256, 0, stream>>>(inp, pos, Xbf);
  transpose_div_kernel<<<dim3(SEQ / 64, FCH / 64), 256, 0, stream>>>(divisor, divT);

  // colfin+colapply after an OUTMODE=1 GEMM (stats already in P1/P2, 8 chunks)
  auto act_norm = [&](unsigned short* dst, int M) {
    colfin_kernel<<<(BSZ * M) / 256, 256, 0, stream>>>(P1, P2, MS, M, 8);
    colapply_kernel<<<dim3(M / 64, NCHF, BSZ), 256, 0, stream>>>(Cfb, MS, dst, M);
  };

  auto run_ff = [&](const float* w0, const float* w1, const float* w2,
                    void* dst, int mode2) {
    cast_bf_kernel<<<(ICH * FCH) / 1024, 256, 0, stream>>>(w0, w0b);
    cast_w1_kernel<<<dim3(ICH / 256, ICH), 256, 0, stream>>>(w1, w1b);
    cast_bf_kernel<<<(FCH * ICH) / 1024, 256, 0, stream>>>(w2, w2b);
    // conv0: M=ICH, K=FCH
    gemm256_kernel<256, 1, 1><<<dim3(SEQ / 256, ICH / 256, BSZ), 512, 131072, stream>>>(
        Xbf, w0b, Cfb, ICH, FCH, P1, P2);
    act_norm(T0b, ICH);
    // conv1: 5 causal taps (tap-outer), M=ICH, K=ICH
    gemm256_kernel<256, 5, 1><<<dim3(SEQ / 256, ICH / 256, BSZ), 512, 131072, stream>>>(
        T0b, w1b, Cfb, ICH, ICH, P1, P2);
    act_norm(T0b, ICH);
    // conv2: M=FCH, K=ICH (BN=128 keeps 256 blocks); fp32 for depth, bf16 else
    if (mode2)
      gemm256_kernel<128, 1, 2><<<dim3(SEQ / 256, FCH / 128, BSZ), 512, 98304, stream>>>(
          T0b, w2b, dst, FCH, ICH, P1, P2);
    else
      gemm256_kernel<128, 1, 0><<<dim3(SEQ / 256, FCH / 128, BSZ), 512, 98304, stream>>>(
          T0b, w2b, dst, FCH, ICH, P1, P2);
  };

  run_ff(w_[0], w_[1], w_[2], Df, 0);   // depth (fp32, feeds cumsum)
  run_ff(w_[3], w_[4], w_[5], Sfb, 1);  // scale (bf16)
  run_ff(w_[6], w_[7], w_[8], Hfb, 1);  // shift (bf16)

  combine_kernel<<<(BSZ * SEQ) / 4, 256, 0, stream>>>(Df, divT, Sfb, Hfb);

  // final act_norm over s (per (b,f)) on combined Df, then transpose + residual
  colred_kernel<<<dim3(FCH / 64, NCHF, BSZ), 256, 0, stream>>>(Df, P1, P2, FCH);
  colfin_kernel<<<(BSZ * FCH) / 256, 256, 0, stream>>>(P1, P2, MS, FCH, NCHF);
  final_apply_kernel<<<dim3(SEQ / 64, FCH / 64, BSZ), 256, 0, stream>>>(
      Df, MS, inp, out);
}